// Round 1
// baseline (1479.869 us; speedup 1.0000x reference)
//
#include <hip/hip_runtime.h>
#include <math.h>

#define NN 100000
#define NE 1600000
#define HIDD 32
#define ATTR_ 16
#define NB 8

__device__ __forceinline__ float silu_(float v){ return v / (1.f + expf(-v)); }

// ---------------- init: h = elem_embed[x] @ W_embed ; agg = 0 ----------------
__global__ void k_init(const int* __restrict__ x, const float* __restrict__ elem,
                       const float* __restrict__ Wemb, float* __restrict__ h,
                       float* __restrict__ agg){
  int idx = blockIdx.x*256 + threadIdx.x;
  if (idx >= NN*HIDD) return;
  int node = idx >> 5, hh = idx & 31;
  int xi = x[node];
  float acc = 0.f;
  #pragma unroll
  for (int a=0; a<ATTR_; a++) acc += elem[xi*ATTR_+a] * Wemb[a*HIDD+hh];
  h[idx] = acc;
  agg[idx] = 0.f;
}

// ---------------- edge kernel: msg + scatter-add ----------------
// block = 256 threads = 8 edges x 32 h-lanes. Per-edge scalars staged in LDS.
__global__ void __launch_bounds__(256) k_edge(
    const float* __restrict__ pos, const int* __restrict__ ei,
    const float* __restrict__ cell, const int* __restrict__ coff,
    const float* __restrict__ Wr_l, const float* __restrict__ br_l,
    const float* __restrict__ h, float* __restrict__ agg){
  __shared__ float sfeat[8][12];   // [edge][rbf0..7, sh0..3]
  __shared__ int   snode[8][2];
  const int e0 = blockIdx.x * 8;
  const int t  = threadIdx.x;
  if (t < 8){
    int e = e0 + t;
    int src = ei[e], dst = ei[NE + e];
    snode[t][0] = src; snode[t][1] = dst;
    float c0 = (float)(coff[e*3+0] - 1);
    float c1 = (float)(coff[e*3+1] - 1);
    float c2 = (float)(coff[e*3+2] - 1);
    float vx = pos[dst*3+0]-pos[src*3+0] + c0*cell[0]+c1*cell[3]+c2*cell[6];
    float vy = pos[dst*3+1]-pos[src*3+1] + c0*cell[1]+c1*cell[4]+c2*cell[7];
    float vz = pos[dst*3+2]-pos[src*3+2] + c0*cell[2]+c1*cell[5]+c2*cell[8];
    float r  = sqrtf(vx*vx+vy*vy+vz*vz);
    float rs = fmaxf(r, 1e-9f);
    float u  = r * 0.2f;
    float env = 0.f;
    if (u < 1.f){
      float u2=u*u, u3=u2*u, u6=u3*u3, u7=u6*u, u8=u7*u;
      env = 1.f - 28.f*u6 + 48.f*u7 - 21.f*u8;
    }
    float sc = env / rs;
    #pragma unroll
    for (int b=0; b<NB; b++)
      sfeat[t][b] = sinf((float)(b+1) * 3.14159265358979323846f * u) * sc;
    float inv = 1.f / rs;
    sfeat[t][8]  = 1.f;
    sfeat[t][9]  = vx*inv;
    sfeat[t][10] = vy*inv;
    sfeat[t][11] = vz*inv;
  }
  __syncthreads();
  const int el = t >> 5, hh = t & 31;
  const int src = snode[el][0], dst = snode[el][1];
  float hs = h[src*HIDD + hh];
  float4 acc = *reinterpret_cast<const float4*>(br_l + 4*hh);
  #pragma unroll
  for (int b=0; b<NB; b++){
    float rb = sfeat[el][b];
    float4 w = *reinterpret_cast<const float4*>(Wr_l + b*128 + 4*hh);
    acc.x += rb*w.x; acc.y += rb*w.y; acc.z += rb*w.z; acc.w += rb*w.w;
  }
  float c = acc.x*sfeat[el][8] + acc.y*sfeat[el][9]
          + acc.z*sfeat[el][10] + acc.w*sfeat[el][11];
  atomicAdd(agg + dst*HIDD + hh, hs*c);
}

// ---------------- node update: h = silu(agg@Wout + elem[x]@Wsc); agg=0 -------
__global__ void k_node(const int* __restrict__ x, const float* __restrict__ elem,
                       const float* __restrict__ Wout_l, const float* __restrict__ Wsc_l,
                       float* __restrict__ h, float* __restrict__ agg){
  int idx = blockIdx.x*256 + threadIdx.x;
  if (idx >= NN*HIDD) return;
  int node = idx >> 5, hh = idx & 31;
  int xi = x[node];
  const float* arow = agg + node*HIDD;
  float acc = 0.f;
  #pragma unroll
  for (int i=0; i<HIDD; i++) acc += arow[i] * Wout_l[i*HIDD+hh];
  #pragma unroll
  for (int a=0; a<ATTR_; a++) acc += elem[xi*ATTR_+a] * Wsc_l[a*HIDD+hh];
  h[idx] = silu_(acc);
  agg[idx] = 0.f;   // safe: this row is read only by this same wave, stores after loads
}

// ---------------- final head: out = silu(h@P1)@P2 ----------------
__global__ void k_final(const float* __restrict__ h, const float* __restrict__ P1,
                        const float* __restrict__ P2, float* __restrict__ out){
  int node = blockIdx.x*256 + threadIdx.x;
  if (node >= NN) return;
  float hr[32];
  const float4* hp = reinterpret_cast<const float4*>(h + node*HIDD);
  #pragma unroll
  for (int i=0; i<8; i++){ float4 v = hp[i]; hr[4*i]=v.x; hr[4*i+1]=v.y; hr[4*i+2]=v.z; hr[4*i+3]=v.w; }
  float o[4] = {0.f,0.f,0.f,0.f};
  #pragma unroll
  for (int j=0; j<32; j++){
    float tj = 0.f;
    #pragma unroll
    for (int i=0; i<32; i++) tj += hr[i]*P1[i*32+j];
    tj = silu_(tj);
    #pragma unroll
    for (int k=0; k<4; k++) o[k] += tj * P2[j*4+k];
  }
  out[node]          = o[0];
  out[NN + node*3+0] = o[1];
  out[NN + node*3+1] = o[2];
  out[NN + node*3+2] = o[3];
}

extern "C" void kernel_launch(void* const* d_in, const int* in_sizes, int n_in,
                              void* d_out, int out_size, void* d_ws, size_t ws_size,
                              hipStream_t stream){
  const int*   x    = (const int*)  d_in[0];
  const float* pos  = (const float*)d_in[1];
  const int*   ei   = (const int*)  d_in[2];
  const float* cell = (const float*)d_in[3];
  const int*   coff = (const int*)  d_in[4];
  const float* elem = (const float*)d_in[5];
  const float* Wemb = (const float*)d_in[6];
  const float* Wr   = (const float*)d_in[7];
  const float* br   = (const float*)d_in[8];
  const float* Wout = (const float*)d_in[9];
  const float* Wsc  = (const float*)d_in[10];
  const float* P1   = (const float*)d_in[11];
  const float* P2   = (const float*)d_in[12];
  float* out = (float*)d_out;

  float* h   = (float*)d_ws;          // NN*32 floats
  float* agg = h + (size_t)NN*HIDD;   // NN*32 floats

  k_init<<<(NN*HIDD+255)/256, 256, 0, stream>>>(x, elem, Wemb, h, agg);
  for (int l=0; l<3; l++){
    k_edge<<<NE/8, 256, 0, stream>>>(pos, ei, cell, coff,
                                     Wr + (size_t)l*NB*HIDD*4, br + (size_t)l*HIDD*4,
                                     h, agg);
    k_node<<<(NN*HIDD+255)/256, 256, 0, stream>>>(x, elem,
                                     Wout + (size_t)l*HIDD*HIDD, Wsc + (size_t)l*ATTR_*HIDD,
                                     h, agg);
  }
  k_final<<<(NN+255)/256, 256, 0, stream>>>(h, P1, P2, out);
}

// Round 2
// 838.657 us; speedup vs baseline: 1.7646x; 1.7646x over previous
//
#include <hip/hip_runtime.h>
#include <math.h>

#define NN 100000
#define NE 1600000
#define HIDD 32
#define ATTR_ 16
#define NB 8
#define EPB 256   // edges per block in k_edge2

__device__ __forceinline__ float silu_(float v){ return v / (1.f + expf(-v)); }

// ---------------- init: h = elem_embed[x] @ W_embed ; agg = 0 ----------------
__global__ void k_init(const int* __restrict__ x, const float* __restrict__ elem,
                       const float* __restrict__ Wemb, float* __restrict__ h,
                       float* __restrict__ agg){
  int idx = blockIdx.x*256 + threadIdx.x;
  if (idx >= NN*HIDD) return;
  int node = idx >> 5, hh = idx & 31;
  int xi = x[node];
  float acc = 0.f;
  #pragma unroll
  for (int a=0; a<ATTR_; a++) acc += elem[xi*ATTR_+a] * Wemb[a*HIDD+hh];
  h[idx] = acc;
  agg[idx] = 0.f;
}

// ================= counting sort of edges by dst =================
__global__ void k_zero_cnt(int* __restrict__ cnt){
  int i = blockIdx.x*256 + threadIdx.x;
  if (i < NN) cnt[i] = 0;
}

__global__ void k_hist(const int* __restrict__ ei, int* __restrict__ cnt){
  int e = blockIdx.x*256 + threadIdx.x;   // NE divisible by 256
  atomicAdd(&cnt[ei[NE + e]], 1);
}

// single-block exclusive scan of cnt[NN] (in place -> start offsets / cursor)
__global__ void __launch_bounds__(1024) k_scan(int* __restrict__ cnt){
  __shared__ int s[1024];
  const int t = threadIdx.x;
  const int C = (NN + 1023) / 1024;
  int beg = t*C, end = beg + C; if (end > NN) end = NN;
  int sum = 0;
  for (int i = beg; i < end; i++) sum += cnt[i];
  s[t] = sum; __syncthreads();
  for (int off = 1; off < 1024; off <<= 1){
    int v = (t >= off) ? s[t-off] : 0;
    __syncthreads();
    s[t] += v;
    __syncthreads();
  }
  int base = (t == 0) ? 0 : s[t-1];
  for (int i = beg; i < end; i++){ int v = cnt[i]; cnt[i] = base; base += v; }
}

__global__ void k_scatter(const int* __restrict__ ei, const int* __restrict__ coff,
                          const float* __restrict__ cell, int* __restrict__ cnt,
                          int* __restrict__ srcs, int* __restrict__ dsts,
                          float* __restrict__ pvec){
  int e = blockIdx.x*256 + threadIdx.x;   // NE divisible by 256
  int src = ei[e], dst = ei[NE + e];
  int p = atomicAdd(&cnt[dst], 1);
  srcs[p] = src; dsts[p] = dst;
  float c0 = (float)(coff[e*3+0] - 1);
  float c1 = (float)(coff[e*3+1] - 1);
  float c2 = (float)(coff[e*3+2] - 1);
  pvec[(size_t)p*3+0] = c0*cell[0] + c1*cell[3] + c2*cell[6];
  pvec[(size_t)p*3+1] = c0*cell[1] + c1*cell[4] + c2*cell[7];
  pvec[(size_t)p*3+2] = c0*cell[2] + c1*cell[5] + c2*cell[8];
}

// ============ sorted edge kernel: msg + chunk-local pre-reduce ============
// block = 256 threads. Phase1: 256 edges' features by 256 threads (full lanes).
// Phase2: 8 groups x 32 h-lanes; each group walks 32 sorted edges with a
// register accumulator, one atomic per dst-change.
__global__ void __launch_bounds__(256) k_edge2(
    const float* __restrict__ pos,
    const int* __restrict__ srcs, const int* __restrict__ dsts,
    const float* __restrict__ pvec,
    const float* __restrict__ Wr_l, const float* __restrict__ br_l,
    const float* __restrict__ h, float* __restrict__ agg){
  __shared__ float sfeat[EPB][12];   // rbf0..7, sh0..3
  __shared__ int ssrc[EPB];
  __shared__ int sdst[EPB];
  const int t = threadIdx.x;
  {
    const int j = blockIdx.x*EPB + t;   // NE divisible by EPB
    int src = srcs[j], dst = dsts[j];
    ssrc[t] = src; sdst[t] = dst;
    float vx = pos[dst*3+0] - pos[src*3+0] + pvec[(size_t)j*3+0];
    float vy = pos[dst*3+1] - pos[src*3+1] + pvec[(size_t)j*3+1];
    float vz = pos[dst*3+2] - pos[src*3+2] + pvec[(size_t)j*3+2];
    float r  = sqrtf(vx*vx + vy*vy + vz*vz);
    float rs = fmaxf(r, 1e-9f);
    float u  = r * 0.2f;
    float env = 0.f;
    if (u < 1.f){
      float u2=u*u, u3=u2*u, u6=u3*u3, u7=u6*u, u8=u7*u;
      env = 1.f - 28.f*u6 + 48.f*u7 - 21.f*u8;
    }
    float sc = env / rs;
    // sin(n*pi*r/5) via Chebyshev recurrence from one sincos
    float s1, c1;
    __sincosf(0.62831853071795864769f * r, &s1, &c1);
    float twoc = 2.f*c1;
    float sp = 0.f, sn = s1;
    #pragma unroll
    for (int b=0; b<NB; b++){ sfeat[t][b] = sn*sc; float nx = twoc*sn - sp; sp = sn; sn = nx; }
    float inv = 1.f / rs;
    sfeat[t][8]  = 1.f;
    sfeat[t][9]  = vx*inv;
    sfeat[t][10] = vy*inv;
    sfeat[t][11] = vz*inv;
  }
  __syncthreads();

  const int g = t >> 5, hh = t & 31, base = g*32;
  // hoist per-hh weights into registers (uniform over the chunk)
  float4 wreg[NB];
  #pragma unroll
  for (int b=0; b<NB; b++)
    wreg[b] = *reinterpret_cast<const float4*>(Wr_l + b*128 + 4*hh);
  const float4 br4 = *reinterpret_cast<const float4*>(br_l + 4*hh);

  float acc = 0.f;
  int cur = sdst[base];
  float buf[16];
  #pragma unroll
  for (int half = 0; half < 2; half++){
    const int kb = base + half*16;
    #pragma unroll
    for (int k=0; k<16; k++) buf[k] = h[(size_t)ssrc[kb+k]*HIDD + hh];
    #pragma unroll
    for (int k=0; k<16; k++){
      const int idx = kb + k;
      int dst = sdst[idx];
      if (dst != cur){ atomicAdd(agg + (size_t)cur*HIDD + hh, acc); acc = 0.f; cur = dst; }
      const float* fr = sfeat[idx];
      float4 f0 = *reinterpret_cast<const float4*>(fr);
      float4 f1 = *reinterpret_cast<const float4*>(fr+4);
      float4 f2 = *reinterpret_cast<const float4*>(fr+8);
      float rb[NB] = {f0.x,f0.y,f0.z,f0.w,f1.x,f1.y,f1.z,f1.w};
      float4 wv = br4;
      #pragma unroll
      for (int b=0; b<NB; b++){
        wv.x += rb[b]*wreg[b].x; wv.y += rb[b]*wreg[b].y;
        wv.z += rb[b]*wreg[b].z; wv.w += rb[b]*wreg[b].w;
      }
      float cval = wv.x*f2.x + wv.y*f2.y + wv.z*f2.z + wv.w*f2.w;
      acc += buf[k]*cval;
    }
  }
  atomicAdd(agg + (size_t)cur*HIDD + hh, acc);
}

// ---------------- fallback edge kernel (round-1 path) ----------------
__global__ void __launch_bounds__(256) k_edge(
    const float* __restrict__ pos, const int* __restrict__ ei,
    const float* __restrict__ cell, const int* __restrict__ coff,
    const float* __restrict__ Wr_l, const float* __restrict__ br_l,
    const float* __restrict__ h, float* __restrict__ agg){
  __shared__ float sfeat[8][12];
  __shared__ int   snode[8][2];
  const int e0 = blockIdx.x * 8;
  const int t  = threadIdx.x;
  if (t < 8){
    int e = e0 + t;
    int src = ei[e], dst = ei[NE + e];
    snode[t][0] = src; snode[t][1] = dst;
    float c0 = (float)(coff[e*3+0] - 1);
    float c1 = (float)(coff[e*3+1] - 1);
    float c2 = (float)(coff[e*3+2] - 1);
    float vx = pos[dst*3+0]-pos[src*3+0] + c0*cell[0]+c1*cell[3]+c2*cell[6];
    float vy = pos[dst*3+1]-pos[src*3+1] + c0*cell[1]+c1*cell[4]+c2*cell[7];
    float vz = pos[dst*3+2]-pos[src*3+2] + c0*cell[2]+c1*cell[5]+c2*cell[8];
    float r  = sqrtf(vx*vx+vy*vy+vz*vz);
    float rs = fmaxf(r, 1e-9f);
    float u  = r * 0.2f;
    float env = 0.f;
    if (u < 1.f){
      float u2=u*u, u3=u2*u, u6=u3*u3, u7=u6*u, u8=u7*u;
      env = 1.f - 28.f*u6 + 48.f*u7 - 21.f*u8;
    }
    float sc = env / rs;
    #pragma unroll
    for (int b=0; b<NB; b++)
      sfeat[t][b] = sinf((float)(b+1) * 3.14159265358979323846f * u * 5.f) * sc;
    float inv = 1.f / rs;
    sfeat[t][8]  = 1.f;
    sfeat[t][9]  = vx*inv;
    sfeat[t][10] = vy*inv;
    sfeat[t][11] = vz*inv;
  }
  __syncthreads();
  const int el = t >> 5, hh = t & 31;
  const int src = snode[el][0], dst = snode[el][1];
  float hs = h[src*HIDD + hh];
  float4 acc = *reinterpret_cast<const float4*>(br_l + 4*hh);
  #pragma unroll
  for (int b=0; b<NB; b++){
    float rb = sfeat[el][b];
    float4 w = *reinterpret_cast<const float4*>(Wr_l + b*128 + 4*hh);
    acc.x += rb*w.x; acc.y += rb*w.y; acc.z += rb*w.z; acc.w += rb*w.w;
  }
  float c = acc.x*sfeat[el][8] + acc.y*sfeat[el][9]
          + acc.z*sfeat[el][10] + acc.w*sfeat[el][11];
  atomicAdd(agg + dst*HIDD + hh, hs*c);
}

// ---------------- node update: h = silu(agg@Wout + elem[x]@Wsc); agg=0 -------
__global__ void k_node(const int* __restrict__ x, const float* __restrict__ elem,
                       const float* __restrict__ Wout_l, const float* __restrict__ Wsc_l,
                       float* __restrict__ h, float* __restrict__ agg){
  int idx = blockIdx.x*256 + threadIdx.x;
  if (idx >= NN*HIDD) return;
  int node = idx >> 5, hh = idx & 31;
  int xi = x[node];
  const float* arow = agg + (size_t)node*HIDD;
  float acc = 0.f;
  #pragma unroll
  for (int i=0; i<HIDD; i++) acc += arow[i] * Wout_l[i*HIDD+hh];
  #pragma unroll
  for (int a=0; a<ATTR_; a++) acc += elem[xi*ATTR_+a] * Wsc_l[a*HIDD+hh];
  h[idx] = silu_(acc);
  agg[idx] = 0.f;   // safe: row read only by this same wave, stores after loads
}

// ---------------- final head: out = silu(h@P1)@P2 ----------------
__global__ void k_final(const float* __restrict__ h, const float* __restrict__ P1,
                        const float* __restrict__ P2, float* __restrict__ out){
  int node = blockIdx.x*256 + threadIdx.x;
  if (node >= NN) return;
  float hr[32];
  const float4* hp = reinterpret_cast<const float4*>(h + (size_t)node*HIDD);
  #pragma unroll
  for (int i=0; i<8; i++){ float4 v = hp[i]; hr[4*i]=v.x; hr[4*i+1]=v.y; hr[4*i+2]=v.z; hr[4*i+3]=v.w; }
  float o[4] = {0.f,0.f,0.f,0.f};
  #pragma unroll
  for (int j=0; j<32; j++){
    float tj = 0.f;
    #pragma unroll
    for (int i=0; i<32; i++) tj += hr[i]*P1[i*32+j];
    tj = silu_(tj);
    #pragma unroll
    for (int k=0; k<4; k++) o[k] += tj * P2[j*4+k];
  }
  out[node]          = o[0];
  out[NN + node*3+0] = o[1];
  out[NN + node*3+1] = o[2];
  out[NN + node*3+2] = o[3];
}

extern "C" void kernel_launch(void* const* d_in, const int* in_sizes, int n_in,
                              void* d_out, int out_size, void* d_ws, size_t ws_size,
                              hipStream_t stream){
  const int*   x    = (const int*)  d_in[0];
  const float* pos  = (const float*)d_in[1];
  const int*   ei   = (const int*)  d_in[2];
  const float* cell = (const float*)d_in[3];
  const int*   coff = (const int*)  d_in[4];
  const float* elem = (const float*)d_in[5];
  const float* Wemb = (const float*)d_in[6];
  const float* Wr   = (const float*)d_in[7];
  const float* br   = (const float*)d_in[8];
  const float* Wout = (const float*)d_in[9];
  const float* Wsc  = (const float*)d_in[10];
  const float* P1   = (const float*)d_in[11];
  const float* P2   = (const float*)d_in[12];
  float* out = (float*)d_out;

  char* w = (char*)d_ws;
  float* h   = (float*)w;  w += (size_t)NN*HIDD*4;
  float* agg = (float*)w;  w += (size_t)NN*HIDD*4;
  int*   cnt  = (int*)w;   w += (size_t)NN*4;
  int*   srcs = (int*)w;   w += (size_t)NE*4;
  int*   dsts = (int*)w;   w += (size_t)NE*4;
  float* pvec = (float*)w; w += (size_t)NE*12;
  const size_t need = (size_t)(w - (char*)d_ws);
  const bool fast = (ws_size >= need);

  if (fast){
    k_zero_cnt<<<(NN+255)/256, 256, 0, stream>>>(cnt);
    k_hist<<<NE/256, 256, 0, stream>>>(ei, cnt);
    k_scan<<<1, 1024, 0, stream>>>(cnt);
    k_scatter<<<NE/256, 256, 0, stream>>>(ei, coff, cell, cnt, srcs, dsts, pvec);
  }
  k_init<<<(NN*HIDD+255)/256, 256, 0, stream>>>(x, elem, Wemb, h, agg);
  for (int l=0; l<3; l++){
    if (fast){
      k_edge2<<<NE/EPB, 256, 0, stream>>>(pos, srcs, dsts, pvec,
                                          Wr + (size_t)l*NB*HIDD*4, br + (size_t)l*HIDD*4,
                                          h, agg);
    } else {
      k_edge<<<NE/8, 256, 0, stream>>>(pos, ei, cell, coff,
                                       Wr + (size_t)l*NB*HIDD*4, br + (size_t)l*HIDD*4,
                                       h, agg);
    }
    k_node<<<(NN*HIDD+255)/256, 256, 0, stream>>>(x, elem,
                                       Wout + (size_t)l*HIDD*HIDD, Wsc + (size_t)l*ATTR_*HIDD,
                                       h, agg);
  }
  k_final<<<(NN+255)/256, 256, 0, stream>>>(h, P1, P2, out);
}

// Round 3
// 668.146 us; speedup vs baseline: 2.2149x; 1.2552x over previous
//
#include <hip/hip_runtime.h>
#include <math.h>

#define NN 100000
#define NE 1600000
#define HIDD 32
#define ATTR_ 16
#define NB 8
#define EPB 256   // edges per block in k_edge2

__device__ __forceinline__ float silu_(float v){ return v / (1.f + expf(-v)); }

// ---------------- init: h = elem_embed[x] @ W_embed ; agg = 0 ----------------
__global__ void k_init(const int* __restrict__ x, const float* __restrict__ elem,
                       const float* __restrict__ Wemb, float* __restrict__ h,
                       float* __restrict__ agg){
  int idx = blockIdx.x*256 + threadIdx.x;
  if (idx >= NN*HIDD) return;
  int node = idx >> 5, hh = idx & 31;
  int xi = x[node];
  float acc = 0.f;
  #pragma unroll
  for (int a=0; a<ATTR_; a++) acc += elem[xi*ATTR_+a] * Wemb[a*HIDD+hh];
  h[idx] = acc;
  agg[idx] = 0.f;
}

// ================= counting sort of edges by dst =================
__global__ void k_zero_cnt(int* __restrict__ cnt){
  int i = blockIdx.x*256 + threadIdx.x;
  if (i < NN) cnt[i] = 0;
}

__global__ void k_hist(const int* __restrict__ ei, int* __restrict__ cnt){
  int e = blockIdx.x*256 + threadIdx.x;   // NE divisible by 256
  atomicAdd(&cnt[ei[NE + e]], 1);
}

// single-block exclusive scan of cnt[NN] (in place -> start offsets / cursor)
__global__ void __launch_bounds__(1024) k_scan(int* __restrict__ cnt){
  __shared__ int s[1024];
  const int t = threadIdx.x;
  const int C = (NN + 1023) / 1024;
  int beg = t*C, end = beg + C; if (end > NN) end = NN;
  int sum = 0;
  for (int i = beg; i < end; i++) sum += cnt[i];
  s[t] = sum; __syncthreads();
  for (int off = 1; off < 1024; off <<= 1){
    int v = (t >= off) ? s[t-off] : 0;
    __syncthreads();
    s[t] += v;
    __syncthreads();
  }
  int base = (t == 0) ? 0 : s[t-1];
  for (int i = beg; i < end; i++){ int v = cnt[i]; cnt[i] = base; base += v; }
}

// scatter: also precompute the FULL edge vector once (kills per-layer pos gathers)
__global__ void k_scatter(const int* __restrict__ ei, const int* __restrict__ coff,
                          const float* __restrict__ cell, const float* __restrict__ pos,
                          int* __restrict__ cnt,
                          int* __restrict__ srcs, int* __restrict__ dsts,
                          float* __restrict__ evec){
  int e = blockIdx.x*256 + threadIdx.x;   // NE divisible by 256
  int src = ei[e], dst = ei[NE + e];
  int p = atomicAdd(&cnt[dst], 1);
  srcs[p] = src; dsts[p] = dst;
  float c0 = (float)(coff[e*3+0] - 1);
  float c1 = (float)(coff[e*3+1] - 1);
  float c2 = (float)(coff[e*3+2] - 1);
  evec[(size_t)p*3+0] = pos[dst*3+0]-pos[src*3+0] + c0*cell[0]+c1*cell[3]+c2*cell[6];
  evec[(size_t)p*3+1] = pos[dst*3+1]-pos[src*3+1] + c0*cell[1]+c1*cell[4]+c2*cell[7];
  evec[(size_t)p*3+2] = pos[dst*3+2]-pos[src*3+2] + c0*cell[2]+c1*cell[5]+c2*cell[8];
}

// ============ sorted edge kernel: msg + chunk-local pre-reduce ============
__global__ void __launch_bounds__(256) k_edge2(
    const int* __restrict__ srcs, const int* __restrict__ dsts,
    const float* __restrict__ evec,
    const float* __restrict__ Wr_l, const float* __restrict__ br_l,
    const float* __restrict__ h, float* __restrict__ agg){
  __shared__ float sfeat[EPB][12];   // rbf0..7, sh0..3
  __shared__ int ssrc[EPB];
  __shared__ int sdst[EPB];
  const int t = threadIdx.x;
  {
    const int j = blockIdx.x*EPB + t;   // NE divisible by EPB
    ssrc[t] = srcs[j]; sdst[t] = dsts[j];
    float vx = evec[(size_t)j*3+0];
    float vy = evec[(size_t)j*3+1];
    float vz = evec[(size_t)j*3+2];
    float r  = sqrtf(vx*vx + vy*vy + vz*vz);
    float rs = fmaxf(r, 1e-9f);
    float u  = r * 0.2f;
    float env = 0.f;
    if (u < 1.f){
      float u2=u*u, u3=u2*u, u6=u3*u3, u7=u6*u, u8=u7*u;
      env = 1.f - 28.f*u6 + 48.f*u7 - 21.f*u8;
    }
    float sc = env / rs;
    // sin(n*pi*r/5) via Chebyshev recurrence from one sincos
    float s1, c1;
    __sincosf(0.62831853071795864769f * r, &s1, &c1);
    float twoc = 2.f*c1;
    float sp = 0.f, sn = s1;
    #pragma unroll
    for (int b=0; b<NB; b++){ sfeat[t][b] = sn*sc; float nx = twoc*sn - sp; sp = sn; sn = nx; }
    float inv = 1.f / rs;
    sfeat[t][8]  = 1.f;
    sfeat[t][9]  = vx*inv;
    sfeat[t][10] = vy*inv;
    sfeat[t][11] = vz*inv;
  }
  __syncthreads();

  const int g = t >> 5, hh = t & 31, base = g*32;
  float4 wreg[NB];
  #pragma unroll
  for (int b=0; b<NB; b++)
    wreg[b] = *reinterpret_cast<const float4*>(Wr_l + b*128 + 4*hh);
  const float4 br4 = *reinterpret_cast<const float4*>(br_l + 4*hh);

  float acc = 0.f;
  int cur = sdst[base];
  float buf[16];
  #pragma unroll
  for (int half = 0; half < 2; half++){
    const int kb = base + half*16;
    #pragma unroll
    for (int k=0; k<16; k++) buf[k] = h[(size_t)ssrc[kb+k]*HIDD + hh];
    #pragma unroll
    for (int k=0; k<16; k++){
      const int idx = kb + k;
      int dst = sdst[idx];
      if (dst != cur){ atomicAdd(agg + (size_t)cur*HIDD + hh, acc); acc = 0.f; cur = dst; }
      const float* fr = sfeat[idx];
      float4 f0 = *reinterpret_cast<const float4*>(fr);
      float4 f1 = *reinterpret_cast<const float4*>(fr+4);
      float4 f2 = *reinterpret_cast<const float4*>(fr+8);
      float rb[NB] = {f0.x,f0.y,f0.z,f0.w,f1.x,f1.y,f1.z,f1.w};
      float4 wv = br4;
      #pragma unroll
      for (int b=0; b<NB; b++){
        wv.x += rb[b]*wreg[b].x; wv.y += rb[b]*wreg[b].y;
        wv.z += rb[b]*wreg[b].z; wv.w += rb[b]*wreg[b].w;
      }
      float cval = wv.x*f2.x + wv.y*f2.y + wv.z*f2.z + wv.w*f2.w;
      acc += buf[k]*cval;
    }
  }
  atomicAdd(agg + (size_t)cur*HIDD + hh, acc);
}

// ---------------- fallback edge kernel (round-1 path, pos-based) ----------------
__global__ void __launch_bounds__(256) k_edge(
    const float* __restrict__ pos, const int* __restrict__ ei,
    const float* __restrict__ cell, const int* __restrict__ coff,
    const float* __restrict__ Wr_l, const float* __restrict__ br_l,
    const float* __restrict__ h, float* __restrict__ agg){
  __shared__ float sfeat[8][12];
  __shared__ int   snode[8][2];
  const int e0 = blockIdx.x * 8;
  const int t  = threadIdx.x;
  if (t < 8){
    int e = e0 + t;
    int src = ei[e], dst = ei[NE + e];
    snode[t][0] = src; snode[t][1] = dst;
    float c0 = (float)(coff[e*3+0] - 1);
    float c1 = (float)(coff[e*3+1] - 1);
    float c2 = (float)(coff[e*3+2] - 1);
    float vx = pos[dst*3+0]-pos[src*3+0] + c0*cell[0]+c1*cell[3]+c2*cell[6];
    float vy = pos[dst*3+1]-pos[src*3+1] + c0*cell[1]+c1*cell[4]+c2*cell[7];
    float vz = pos[dst*3+2]-pos[src*3+2] + c0*cell[2]+c1*cell[5]+c2*cell[8];
    float r  = sqrtf(vx*vx+vy*vy+vz*vz);
    float rs = fmaxf(r, 1e-9f);
    float u  = r * 0.2f;
    float env = 0.f;
    if (u < 1.f){
      float u2=u*u, u3=u2*u, u6=u3*u3, u7=u6*u, u8=u7*u;
      env = 1.f - 28.f*u6 + 48.f*u7 - 21.f*u8;
    }
    float sc = env / rs;
    #pragma unroll
    for (int b=0; b<NB; b++)
      sfeat[t][b] = sinf((float)(b+1) * 3.14159265358979323846f * u) * sc;
    float inv = 1.f / rs;
    sfeat[t][8]  = 1.f;
    sfeat[t][9]  = vx*inv;
    sfeat[t][10] = vy*inv;
    sfeat[t][11] = vz*inv;
  }
  __syncthreads();
  const int el = t >> 5, hh = t & 31;
  const int src = snode[el][0], dst = snode[el][1];
  float hs = h[src*HIDD + hh];
  float4 acc = *reinterpret_cast<const float4*>(br_l + 4*hh);
  #pragma unroll
  for (int b=0; b<NB; b++){
    float rb = sfeat[el][b];
    float4 w = *reinterpret_cast<const float4*>(Wr_l + b*128 + 4*hh);
    acc.x += rb*w.x; acc.y += rb*w.y; acc.z += rb*w.z; acc.w += rb*w.w;
  }
  float c = acc.x*sfeat[el][8] + acc.y*sfeat[el][9]
          + acc.z*sfeat[el][10] + acc.w*sfeat[el][11];
  atomicAdd(agg + dst*HIDD + hh, hs*c);
}

// ---------------- node update: h = silu(agg@Wout + elem[x]@Wsc); agg=0 -------
__global__ void k_node(const int* __restrict__ x, const float* __restrict__ elem,
                       const float* __restrict__ Wout_l, const float* __restrict__ Wsc_l,
                       float* __restrict__ h, float* __restrict__ agg){
  int idx = blockIdx.x*256 + threadIdx.x;
  if (idx >= NN*HIDD) return;
  int node = idx >> 5, hh = idx & 31;
  int xi = x[node];
  const float* arow = agg + (size_t)node*HIDD;
  float acc = 0.f;
  #pragma unroll
  for (int i=0; i<HIDD; i++) acc += arow[i] * Wout_l[i*HIDD+hh];
  #pragma unroll
  for (int a=0; a<ATTR_; a++) acc += elem[xi*ATTR_+a] * Wsc_l[a*HIDD+hh];
  h[idx] = silu_(acc);
  agg[idx] = 0.f;   // safe: row read only by this same wave, stores after loads
}

// ---------------- final head: node,j-parallel, P1 in LDS, shfl reduce --------
__global__ void __launch_bounds__(256) k_final2(
    const float* __restrict__ h, const float* __restrict__ P1,
    const float* __restrict__ P2, float* __restrict__ out){
  __shared__ float sP1[32][32];
  __shared__ float sh[8][32];
  const int t = threadIdx.x;
  {
    float4 v = reinterpret_cast<const float4*>(P1)[t];   // 256*4 = 1024 elems
    int r = (t*4) >> 5, c = (t*4) & 31;
    sP1[r][c]   = v.x; sP1[r][c+1] = v.y;
    sP1[r][c+2] = v.z; sP1[r][c+3] = v.w;
  }
  const int node0 = blockIdx.x * 8;
  ((float*)sh)[t] = h[(size_t)node0*HIDD + t];           // coalesced 256 floats
  __syncthreads();
  const int g = t >> 5, j = t & 31;
  const int node = node0 + g;
  float tj = 0.f;
  #pragma unroll
  for (int i=0; i<32; i++) tj += sh[g][i] * sP1[i][j];   // broadcast + stride-1
  tj = silu_(tj);
  float4 p2 = reinterpret_cast<const float4*>(P2)[j];    // P2 row j
  float o0 = tj*p2.x, o1 = tj*p2.y, o2 = tj*p2.z, o3 = tj*p2.w;
  #pragma unroll
  for (int m=1; m<32; m<<=1){
    o0 += __shfl_xor(o0, m);
    o1 += __shfl_xor(o1, m);
    o2 += __shfl_xor(o2, m);
    o3 += __shfl_xor(o3, m);
  }
  if (j == 0){
    out[node]            = o0;
    out[NN + node*3 + 0] = o1;
    out[NN + node*3 + 1] = o2;
    out[NN + node*3 + 2] = o3;
  }
}

extern "C" void kernel_launch(void* const* d_in, const int* in_sizes, int n_in,
                              void* d_out, int out_size, void* d_ws, size_t ws_size,
                              hipStream_t stream){
  const int*   x    = (const int*)  d_in[0];
  const float* pos  = (const float*)d_in[1];
  const int*   ei   = (const int*)  d_in[2];
  const float* cell = (const float*)d_in[3];
  const int*   coff = (const int*)  d_in[4];
  const float* elem = (const float*)d_in[5];
  const float* Wemb = (const float*)d_in[6];
  const float* Wr   = (const float*)d_in[7];
  const float* br   = (const float*)d_in[8];
  const float* Wout = (const float*)d_in[9];
  const float* Wsc  = (const float*)d_in[10];
  const float* P1   = (const float*)d_in[11];
  const float* P2   = (const float*)d_in[12];
  float* out = (float*)d_out;

  char* w = (char*)d_ws;
  float* h    = (float*)w; w += (size_t)NN*HIDD*4;
  float* agg  = (float*)w; w += (size_t)NN*HIDD*4;
  int*   cnt  = (int*)w;   w += (size_t)NN*4;
  int*   srcs = (int*)w;   w += (size_t)NE*4;
  int*   dsts = (int*)w;   w += (size_t)NE*4;
  float* evec = (float*)w; w += (size_t)NE*12;
  const size_t need = (size_t)(w - (char*)d_ws);
  const bool fast = (ws_size >= need);

  if (fast){
    k_zero_cnt<<<(NN+255)/256, 256, 0, stream>>>(cnt);
    k_hist<<<NE/256, 256, 0, stream>>>(ei, cnt);
    k_scan<<<1, 1024, 0, stream>>>(cnt);
    k_scatter<<<NE/256, 256, 0, stream>>>(ei, coff, cell, pos, cnt, srcs, dsts, evec);
  }
  k_init<<<(NN*HIDD+255)/256, 256, 0, stream>>>(x, elem, Wemb, h, agg);
  for (int l=0; l<3; l++){
    if (fast){
      k_edge2<<<NE/EPB, 256, 0, stream>>>(srcs, dsts, evec,
                                          Wr + (size_t)l*NB*HIDD*4, br + (size_t)l*HIDD*4,
                                          h, agg);
    } else {
      k_edge<<<NE/8, 256, 0, stream>>>(pos, ei, cell, coff,
                                       Wr + (size_t)l*NB*HIDD*4, br + (size_t)l*HIDD*4,
                                       h, agg);
    }
    k_node<<<(NN*HIDD+255)/256, 256, 0, stream>>>(x, elem,
                                       Wout + (size_t)l*HIDD*HIDD, Wsc + (size_t)l*ATTR_*HIDD,
                                       h, agg);
  }
  k_final2<<<NN/8, 256, 0, stream>>>(h, P1, P2, out);
}

// Round 4
// 514.469 us; speedup vs baseline: 2.8765x; 1.2987x over previous
//
#include <hip/hip_runtime.h>
#include <math.h>

#define NN 100000
#define NE 1600000
#define HIDD 32
#define ATTR_ 16
#define NB 8
#define EPB 256        // edges per block in k_edge2
#define SCAN_BLK 98    // ceil(NN/1024)

__device__ __forceinline__ float silu_(float v){ return v / (1.f + expf(-v)); }

// ---------------- init: h = elem_embed[x] @ W_embed ; agg = 0 ----------------
__global__ void k_init(const int* __restrict__ x, const float* __restrict__ elem,
                       const float* __restrict__ Wemb, float* __restrict__ h,
                       float* __restrict__ agg){
  int idx = blockIdx.x*256 + threadIdx.x;
  if (idx >= NN*HIDD) return;
  int node = idx >> 5, hh = idx & 31;
  int xi = x[node];
  float acc = 0.f;
  #pragma unroll
  for (int a=0; a<ATTR_; a++) acc += elem[xi*ATTR_+a] * Wemb[a*HIDD+hh];
  h[idx] = acc;
  agg[idx] = 0.f;
}

// ================= counting sort of edges by dst =================
__global__ void k_zero_cnt(int* __restrict__ cnt){
  int i = blockIdx.x*256 + threadIdx.x;
  if (i < NN) cnt[i] = 0;
}

__global__ void k_hist(const int* __restrict__ ei, int* __restrict__ cnt){
  int e = blockIdx.x*256 + threadIdx.x;   // NE divisible by 256
  atomicAdd(&cnt[ei[NE + e]], 1);
}

// ---- hierarchical exclusive scan of cnt[NN]: A (block scan) ----
__global__ void __launch_bounds__(1024) k_scanA(int* __restrict__ cnt,
                                                int* __restrict__ bsum){
  __shared__ int s[1024];
  const int t = threadIdx.x;
  const int i = blockIdx.x*1024 + t;
  int v = (i < NN) ? cnt[i] : 0;
  s[t] = v; __syncthreads();
  #pragma unroll
  for (int off = 1; off < 1024; off <<= 1){
    int u = (t >= off) ? s[t-off] : 0;
    __syncthreads();
    s[t] += u;
    __syncthreads();
  }
  if (i < NN) cnt[i] = s[t] - v;            // exclusive within block
  if (t == 1023) bsum[blockIdx.x] = s[t];   // block total
}

// ---- B: scan the block totals (single tiny block) ----
__global__ void __launch_bounds__(128) k_scanB(int* __restrict__ bsum){
  __shared__ int s[128];
  const int t = threadIdx.x;
  int v = (t < SCAN_BLK) ? bsum[t] : 0;
  s[t] = v; __syncthreads();
  #pragma unroll
  for (int off = 1; off < 128; off <<= 1){
    int u = (t >= off) ? s[t-off] : 0;
    __syncthreads();
    s[t] += u;
    __syncthreads();
  }
  if (t < SCAN_BLK) bsum[t] = s[t] - v;     // exclusive
}

// ---- C: add block offsets back ----
__global__ void __launch_bounds__(1024) k_scanC(int* __restrict__ cnt,
                                                const int* __restrict__ bsum){
  const int i = blockIdx.x*1024 + threadIdx.x;
  if (i < NN) cnt[i] += bsum[blockIdx.x];
}

// scatter: also precompute the FULL edge vector once
__global__ void k_scatter(const int* __restrict__ ei, const int* __restrict__ coff,
                          const float* __restrict__ cell, const float* __restrict__ pos,
                          int* __restrict__ cnt,
                          int* __restrict__ srcs, int* __restrict__ dsts,
                          float* __restrict__ evec){
  int e = blockIdx.x*256 + threadIdx.x;   // NE divisible by 256
  int src = ei[e], dst = ei[NE + e];
  int p = atomicAdd(&cnt[dst], 1);
  srcs[p] = src; dsts[p] = dst;
  float c0 = (float)(coff[e*3+0] - 1);
  float c1 = (float)(coff[e*3+1] - 1);
  float c2 = (float)(coff[e*3+2] - 1);
  evec[(size_t)p*3+0] = pos[dst*3+0]-pos[src*3+0] + c0*cell[0]+c1*cell[3]+c2*cell[6];
  evec[(size_t)p*3+1] = pos[dst*3+1]-pos[src*3+1] + c0*cell[1]+c1*cell[4]+c2*cell[7];
  evec[(size_t)p*3+2] = pos[dst*3+2]-pos[src*3+2] + c0*cell[2]+c1*cell[5]+c2*cell[8];
}

// ============ sorted edge kernel: msg + chunk-local pre-reduce ============
__global__ void __launch_bounds__(256) k_edge2(
    const int* __restrict__ srcs, const int* __restrict__ dsts,
    const float* __restrict__ evec,
    const float* __restrict__ Wr_l, const float* __restrict__ br_l,
    const float* __restrict__ h, float* __restrict__ agg){
  __shared__ float sfeat[EPB][12];   // rbf0..7, sh0..3
  __shared__ int ssrc[EPB];
  __shared__ int sdst[EPB];
  const int t = threadIdx.x;
  {
    const int j = blockIdx.x*EPB + t;   // NE divisible by EPB
    ssrc[t] = srcs[j]; sdst[t] = dsts[j];
    float vx = evec[(size_t)j*3+0];
    float vy = evec[(size_t)j*3+1];
    float vz = evec[(size_t)j*3+2];
    float r  = sqrtf(vx*vx + vy*vy + vz*vz);
    float rs = fmaxf(r, 1e-9f);
    float u  = r * 0.2f;
    float env = 0.f;
    if (u < 1.f){
      float u2=u*u, u3=u2*u, u6=u3*u3, u7=u6*u, u8=u7*u;
      env = 1.f - 28.f*u6 + 48.f*u7 - 21.f*u8;
    }
    float sc = env / rs;
    float s1, c1;
    __sincosf(0.62831853071795864769f * r, &s1, &c1);
    float twoc = 2.f*c1;
    float sp = 0.f, sn = s1;
    #pragma unroll
    for (int b=0; b<NB; b++){ sfeat[t][b] = sn*sc; float nx = twoc*sn - sp; sp = sn; sn = nx; }
    float inv = 1.f / rs;
    sfeat[t][8]  = 1.f;
    sfeat[t][9]  = vx*inv;
    sfeat[t][10] = vy*inv;
    sfeat[t][11] = vz*inv;
  }
  __syncthreads();

  const int g = t >> 5, hh = t & 31, base = g*32;
  float4 wreg[NB];
  #pragma unroll
  for (int b=0; b<NB; b++)
    wreg[b] = *reinterpret_cast<const float4*>(Wr_l + b*128 + 4*hh);
  const float4 br4 = *reinterpret_cast<const float4*>(br_l + 4*hh);

  float acc = 0.f;
  int cur = sdst[base];
  float buf[16];
  #pragma unroll
  for (int half = 0; half < 2; half++){
    const int kb = base + half*16;
    #pragma unroll
    for (int k=0; k<16; k++) buf[k] = h[(size_t)ssrc[kb+k]*HIDD + hh];
    #pragma unroll
    for (int k=0; k<16; k++){
      const int idx = kb + k;
      int dst = sdst[idx];
      if (dst != cur){ atomicAdd(agg + (size_t)cur*HIDD + hh, acc); acc = 0.f; cur = dst; }
      const float* fr = sfeat[idx];
      float4 f0 = *reinterpret_cast<const float4*>(fr);
      float4 f1 = *reinterpret_cast<const float4*>(fr+4);
      float4 f2 = *reinterpret_cast<const float4*>(fr+8);
      float rb[NB] = {f0.x,f0.y,f0.z,f0.w,f1.x,f1.y,f1.z,f1.w};
      float4 wv = br4;
      #pragma unroll
      for (int b=0; b<NB; b++){
        wv.x += rb[b]*wreg[b].x; wv.y += rb[b]*wreg[b].y;
        wv.z += rb[b]*wreg[b].z; wv.w += rb[b]*wreg[b].w;
      }
      float cval = wv.x*f2.x + wv.y*f2.y + wv.z*f2.z + wv.w*f2.w;
      acc += buf[k]*cval;
    }
  }
  atomicAdd(agg + (size_t)cur*HIDD + hh, acc);
}

// ---------------- fallback edge kernel (round-1 path, pos-based) -------------
__global__ void __launch_bounds__(256) k_edge(
    const float* __restrict__ pos, const int* __restrict__ ei,
    const float* __restrict__ cell, const int* __restrict__ coff,
    const float* __restrict__ Wr_l, const float* __restrict__ br_l,
    const float* __restrict__ h, float* __restrict__ agg){
  __shared__ float sfeat[8][12];
  __shared__ int   snode[8][2];
  const int e0 = blockIdx.x * 8;
  const int t  = threadIdx.x;
  if (t < 8){
    int e = e0 + t;
    int src = ei[e], dst = ei[NE + e];
    snode[t][0] = src; snode[t][1] = dst;
    float c0 = (float)(coff[e*3+0] - 1);
    float c1 = (float)(coff[e*3+1] - 1);
    float c2 = (float)(coff[e*3+2] - 1);
    float vx = pos[dst*3+0]-pos[src*3+0] + c0*cell[0]+c1*cell[3]+c2*cell[6];
    float vy = pos[dst*3+1]-pos[src*3+1] + c0*cell[1]+c1*cell[4]+c2*cell[7];
    float vz = pos[dst*3+2]-pos[src*3+2] + c0*cell[2]+c1*cell[5]+c2*cell[8];
    float r  = sqrtf(vx*vx+vy*vy+vz*vz);
    float rs = fmaxf(r, 1e-9f);
    float u  = r * 0.2f;
    float env = 0.f;
    if (u < 1.f){
      float u2=u*u, u3=u2*u, u6=u3*u3, u7=u6*u, u8=u7*u;
      env = 1.f - 28.f*u6 + 48.f*u7 - 21.f*u8;
    }
    float sc = env / rs;
    #pragma unroll
    for (int b=0; b<NB; b++)
      sfeat[t][b] = sinf((float)(b+1) * 3.14159265358979323846f * u) * sc;
    float inv = 1.f / rs;
    sfeat[t][8]  = 1.f;
    sfeat[t][9]  = vx*inv;
    sfeat[t][10] = vy*inv;
    sfeat[t][11] = vz*inv;
  }
  __syncthreads();
  const int el = t >> 5, hh = t & 31;
  const int src = snode[el][0], dst = snode[el][1];
  float hs = h[src*HIDD + hh];
  float4 acc = *reinterpret_cast<const float4*>(br_l + 4*hh);
  #pragma unroll
  for (int b=0; b<NB; b++){
    float rb = sfeat[el][b];
    float4 w = *reinterpret_cast<const float4*>(Wr_l + b*128 + 4*hh);
    acc.x += rb*w.x; acc.y += rb*w.y; acc.z += rb*w.z; acc.w += rb*w.w;
  }
  float c = acc.x*sfeat[el][8] + acc.y*sfeat[el][9]
          + acc.z*sfeat[el][10] + acc.w*sfeat[el][11];
  atomicAdd(agg + dst*HIDD + hh, hs*c);
}

// ---------------- node update: h = silu(agg@Wout + elem[x]@Wsc); agg=0 -------
__global__ void k_node(const int* __restrict__ x, const float* __restrict__ elem,
                       const float* __restrict__ Wout_l, const float* __restrict__ Wsc_l,
                       float* __restrict__ h, float* __restrict__ agg){
  int idx = blockIdx.x*256 + threadIdx.x;
  if (idx >= NN*HIDD) return;
  int node = idx >> 5, hh = idx & 31;
  int xi = x[node];
  const float* arow = agg + (size_t)node*HIDD;
  float acc = 0.f;
  #pragma unroll
  for (int i=0; i<HIDD; i++) acc += arow[i] * Wout_l[i*HIDD+hh];
  #pragma unroll
  for (int a=0; a<ATTR_; a++) acc += elem[xi*ATTR_+a] * Wsc_l[a*HIDD+hh];
  h[idx] = silu_(acc);
  agg[idx] = 0.f;   // safe: row read only by this same wave, stores after loads
}

// ---------------- final head: node,j-parallel, P1 in LDS, shfl reduce --------
__global__ void __launch_bounds__(256) k_final2(
    const float* __restrict__ h, const float* __restrict__ P1,
    const float* __restrict__ P2, float* __restrict__ out){
  __shared__ float sP1[32][32];
  __shared__ float sh[8][32];
  const int t = threadIdx.x;
  {
    float4 v = reinterpret_cast<const float4*>(P1)[t];   // 256*4 = 1024 elems
    int r = (t*4) >> 5, c = (t*4) & 31;
    sP1[r][c]   = v.x; sP1[r][c+1] = v.y;
    sP1[r][c+2] = v.z; sP1[r][c+3] = v.w;
  }
  const int node0 = blockIdx.x * 8;
  ((float*)sh)[t] = h[(size_t)node0*HIDD + t];           // coalesced 256 floats
  __syncthreads();
  const int g = t >> 5, j = t & 31;
  const int node = node0 + g;
  float tj = 0.f;
  #pragma unroll
  for (int i=0; i<32; i++) tj += sh[g][i] * sP1[i][j];   // broadcast + stride-1
  tj = silu_(tj);
  float4 p2 = reinterpret_cast<const float4*>(P2)[j];    // P2 row j
  float o0 = tj*p2.x, o1 = tj*p2.y, o2 = tj*p2.z, o3 = tj*p2.w;
  #pragma unroll
  for (int m=1; m<32; m<<=1){
    o0 += __shfl_xor(o0, m);
    o1 += __shfl_xor(o1, m);
    o2 += __shfl_xor(o2, m);
    o3 += __shfl_xor(o3, m);
  }
  if (j == 0){
    out[node]            = o0;
    out[NN + node*3 + 0] = o1;
    out[NN + node*3 + 1] = o2;
    out[NN + node*3 + 2] = o3;
  }
}

extern "C" void kernel_launch(void* const* d_in, const int* in_sizes, int n_in,
                              void* d_out, int out_size, void* d_ws, size_t ws_size,
                              hipStream_t stream){
  const int*   x    = (const int*)  d_in[0];
  const float* pos  = (const float*)d_in[1];
  const int*   ei   = (const int*)  d_in[2];
  const float* cell = (const float*)d_in[3];
  const int*   coff = (const int*)  d_in[4];
  const float* elem = (const float*)d_in[5];
  const float* Wemb = (const float*)d_in[6];
  const float* Wr   = (const float*)d_in[7];
  const float* br   = (const float*)d_in[8];
  const float* Wout = (const float*)d_in[9];
  const float* Wsc  = (const float*)d_in[10];
  const float* P1   = (const float*)d_in[11];
  const float* P2   = (const float*)d_in[12];
  float* out = (float*)d_out;

  char* w = (char*)d_ws;
  float* h    = (float*)w; w += (size_t)NN*HIDD*4;
  float* agg  = (float*)w; w += (size_t)NN*HIDD*4;
  int*   cnt  = (int*)w;   w += (size_t)NN*4;
  int*   srcs = (int*)w;   w += (size_t)NE*4;
  int*   dsts = (int*)w;   w += (size_t)NE*4;
  float* evec = (float*)w; w += (size_t)NE*12;
  const size_t need = (size_t)(w - (char*)d_ws);
  const bool fast = (ws_size >= need);
  int* bsum = (int*)evec;   // scan scratch aliases evec (written later by k_scatter)

  if (fast){
    k_zero_cnt<<<(NN+255)/256, 256, 0, stream>>>(cnt);
    k_hist<<<NE/256, 256, 0, stream>>>(ei, cnt);
    k_scanA<<<SCAN_BLK, 1024, 0, stream>>>(cnt, bsum);
    k_scanB<<<1, 128, 0, stream>>>(bsum);
    k_scanC<<<SCAN_BLK, 1024, 0, stream>>>(cnt, bsum);
    k_scatter<<<NE/256, 256, 0, stream>>>(ei, coff, cell, pos, cnt, srcs, dsts, evec);
  }
  k_init<<<(NN*HIDD+255)/256, 256, 0, stream>>>(x, elem, Wemb, h, agg);
  for (int l=0; l<3; l++){
    if (fast){
      k_edge2<<<NE/EPB, 256, 0, stream>>>(srcs, dsts, evec,
                                          Wr + (size_t)l*NB*HIDD*4, br + (size_t)l*HIDD*4,
                                          h, agg);
    } else {
      k_edge<<<NE/8, 256, 0, stream>>>(pos, ei, cell, coff,
                                       Wr + (size_t)l*NB*HIDD*4, br + (size_t)l*HIDD*4,
                                       h, agg);
    }
    k_node<<<(NN*HIDD+255)/256, 256, 0, stream>>>(x, elem,
                                       Wout + (size_t)l*HIDD*HIDD, Wsc + (size_t)l*ATTR_*HIDD,
                                       h, agg);
  }
  k_final2<<<NN/8, 256, 0, stream>>>(h, P1, P2, out);
}